// Round 1
// baseline (438.316 us; speedup 1.0000x reference)
//
#include <hip/hip_runtime.h>
#include <hip/hip_bf16.h>
#include <stdint.h>

// Problem constants
#define NU 4000
#define NI 4000
#define RR 5
#define MM 256
#define OUTD 75
#define SIDE 64
#define FDIM 128
#define MPAD 4032           // 63 * 64

typedef float f32x4 __attribute__((ext_vector_type(4)));
typedef short bf16x8 __attribute__((ext_vector_type(8)));
typedef unsigned int u32x4 __attribute__((ext_vector_type(4)));

// ---------------------------------------------------------------------------
// K1: fused adj->int8 (both layouts) + degree counts Nu (row nz) / Nv (col nz)
// grid (63, 63) tiles of 64x64, block 256 (4 waves, wave = one row sweep)
// ---------------------------------------------------------------------------
__global__ __launch_bounds__(256) void k_trans(const int* __restrict__ adj,
                                               int8_t* __restrict__ a8,
                                               int8_t* __restrict__ a8t,
                                               int* __restrict__ Nu,
                                               int* __restrict__ Nv) {
  __shared__ int8_t lt[64][65];
  __shared__ int rowc[64];
  __shared__ int colp[4][64];
  const int i0 = blockIdx.x * 64;
  const int u0 = blockIdx.y * 64;
  const int t = threadIdx.x;
  const int w = t >> 6, lane = t & 63;
  int mycol = 0;
  for (int rep = 0; rep < 16; rep++) {
    const int r = rep * 4 + w;
    const int u = u0 + r, i = i0 + lane;
    int a = (u < NU && i < NI) ? adj[(size_t)u * NI + i] : 0;
    const int nz = (a > 0) ? 1 : 0;
    unsigned long long bal = __ballot(nz);
    if (lane == 0) rowc[r] = (int)__popcll(bal);
    mycol += nz;
    if (i < NI) a8[(size_t)u * NI + i] = (int8_t)a;   // u < MPAD always
    lt[lane][r] = (int8_t)a;                          // transposed staging
  }
  colp[w][lane] = mycol;
  __syncthreads();
  for (int rep = 0; rep < 16; rep++) {
    const int r = rep * 4 + w;
    const int it = i0 + r, uu = u0 + lane;
    if (uu < NU) a8t[(size_t)it * NU + uu] = lt[r][lane];
  }
  if (t < 64) {
    const int cc = colp[0][t] + colp[1][t] + colp[2][t] + colp[3][t];
    if (i0 + t < NI && cc) atomicAdd(&Nv[i0 + t], cc);
    if (u0 + t < NU && rowc[t]) atomicAdd(&Nu[u0 + t], rowc[t]);
  }
}

// ---------------------------------------------------------------------------
// K2: P build.  Pu[r][m][i] = msg_W[r][m][NU+i] * rsqrt(Nv[i])  (bf16)
//               Pv[r][m][u] = msg_W[r][m][u]    * rsqrt(Nu[u])  (bf16)
// grid 1280 = r*256+m rows, block 256
// ---------------------------------------------------------------------------
__global__ __launch_bounds__(256) void k_pbuild(const float* __restrict__ msgW,
                                                const int* __restrict__ Nu,
                                                const int* __restrict__ Nv,
                                                __hip_bfloat16* __restrict__ Pu,
                                                __hip_bfloat16* __restrict__ Pv) {
  const int b = blockIdx.x;                 // r*256 + m
  const float* src = msgW + (size_t)b * (NU + NI);
  for (int idx = threadIdx.x; idx < NU; idx += 256) {
    const int cu = Nu[idx], cv = Nv[idx];
    const float su = cu > 0 ? rsqrtf((float)cu) : 0.f;
    const float sv = cv > 0 ? rsqrtf((float)cv) : 0.f;
    Pv[(size_t)b * NU + idx] = __float2bfloat16(src[idx] * su);
    Pu[(size_t)b * NI + idx] = __float2bfloat16(src[NU + idx] * sv);
  }
}

// ---------------------------------------------------------------------------
// K3: one-hot bf16 MFMA GEMM.  H[row][m] = relu(rsqrt(cnt[row]) *
//        sum_k sum_r (A8[row][k]==r+1) * P[r][m][k])
// A-fragments synthesized in registers from int8 adj; B straight from global.
// BM=64 BN=128 BK=32, 4 waves (2x2) of 32x64.  grid 252 = 2 sides * 63 * 2.
// ---------------------------------------------------------------------------
__global__ __launch_bounds__(256) void k_gemm(const int8_t* __restrict__ Au,
                                              const int8_t* __restrict__ Av,
                                              const __hip_bfloat16* __restrict__ Pu,
                                              const __hip_bfloat16* __restrict__ Pv,
                                              const int* __restrict__ Nu,
                                              const int* __restrict__ Nv,
                                              float* __restrict__ Hu,
                                              float* __restrict__ Hv) {
  const int bid = blockIdx.x;
  const int side = bid / 126;
  const int tt = bid % 126;
  const int bn = tt / 63, bm = tt % 63;
  const int8_t* __restrict__ A8 = side ? Av : Au;
  const __hip_bfloat16* __restrict__ P = side ? Pv : Pu;
  const int* __restrict__ cnt = side ? Nv : Nu;
  float* __restrict__ Hout = side ? Hv : Hu;

  const int t = threadIdx.x, l = t & 63, w = t >> 6;
  const int wr = w >> 1, wc = w & 1;
  const int l15 = l & 15, l4 = l >> 4;

  const int arow = bm * 64 + wr * 32 + l15;          // + g*16
  const int ncol = bn * 128 + wc * 64 + l15;         // + c*16
  const int8_t* pa = A8 + (size_t)arow * 4000 + 8 * l4;
  const __hip_bfloat16* pb = P + (size_t)ncol * 4000 + 8 * l4;

  f32x4 acc[2][4] = {};

  for (int k = 0; k < 4000; k += 32) {
    // B fragments: elem j = P[r][ncol+c*16][k + 8*l4 + j]  (i-contiguous)
    bf16x8 bfr[5][4];
#pragma unroll
    for (int r = 0; r < 5; r++)
#pragma unroll
      for (int c = 0; c < 4; c++)
        bfr[r][c] = *(const bf16x8*)(pb + (size_t)(r * 256 + c * 16) * 4000 + k);

#pragma unroll
    for (int g = 0; g < 2; g++) {
      // 8 adj bytes for this lane's A-fragment row
      uint2 av = *(const uint2*)(pa + (size_t)g * 16 * 4000 + k);
      // unpack to bytes [a_lo, 1, a_hi, 1] per dword (sentinel 1 absorbs borrow)
      uint32_t x0 = __builtin_amdgcn_perm(0x01010101u, av.x, 0x04010400u);
      uint32_t x1 = __builtin_amdgcn_perm(0x01010101u, av.x, 0x04030402u);
      uint32_t x2 = __builtin_amdgcn_perm(0x01010101u, av.y, 0x04010400u);
      uint32_t x3 = __builtin_amdgcn_perm(0x01010101u, av.y, 0x04030402u);
      uint32_t x[4] = {x0, x1, x2, x3};
#pragma unroll
      for (int r = 0; r < 5; r++) {
        const uint32_t rrc = (uint32_t)(r + 1) * 0x00010001u;
        u32x4 oh;
#pragma unroll
        for (int d = 0; d < 4; d++) {
          uint32_t tv = x[d] ^ rrc;      // 0 in a-byte iff match
          tv = tv - 0x00010001u;         // match -> 0xFF in low byte of half
          tv = tv & 0x00800080u;         // match -> 0x80 per half
          tv = (tv << 7) - tv;           // *127 -> 0x3F80 (bf16 1.0) per half
          oh[d] = tv;
        }
        const bf16x8 af = __builtin_bit_cast(bf16x8, oh);
#pragma unroll
        for (int c = 0; c < 4; c++)
          acc[g][c] = __builtin_amdgcn_mfma_f32_16x16x32_bf16(af, bfr[r][c],
                                                              acc[g][c], 0, 0, 0);
      }
    }
  }

  // epilogue: scale by rsqrt(cnt[row]), relu, store f32
#pragma unroll
  for (int g = 0; g < 2; g++) {
    const int rowb = bm * 64 + wr * 32 + g * 16 + l4 * 4;
#pragma unroll
    for (int c = 0; c < 4; c++) {
      const int col = bn * 128 + wc * 64 + c * 16 + l15;
#pragma unroll
      for (int q = 0; q < 4; q++) {
        const int orow = rowb + q;
        if (orow < 4000) {
          const int cv = cnt[orow];
          const float s = cv > 0 ? rsqrtf((float)cv) : 0.f;
          const float v = acc[g][c][q] * s;
          Hout[(size_t)orow * 256 + col] = v > 0.f ? v : 0.f;
        }
      }
    }
  }
}

// ---------------------------------------------------------------------------
// K4: stage 2.  Per 4 rows: F = relu(sf@W1^T + b1); out = relu(H@dW^T + F@W2^T)
// grid 2000 = 2 sides * 1000, block 256 = 4 rows * 64 threads
// ---------------------------------------------------------------------------
__global__ __launch_bounds__(256) void k_out(const float* __restrict__ Hu,
                                             const float* __restrict__ Hv,
                                             const float* __restrict__ usf,
                                             const float* __restrict__ vsf,
                                             const float* __restrict__ dW,
                                             const float* __restrict__ uW1,
                                             const float* __restrict__ ub1,
                                             const float* __restrict__ uW2,
                                             const float* __restrict__ vW1,
                                             const float* __restrict__ vb1,
                                             const float* __restrict__ vW2,
                                             float* __restrict__ out) {
  const int bid = blockIdx.x;
  const int side = bid / 1000;
  const int u0 = (bid % 1000) * 4;
  const float* __restrict__ H = side ? Hv : Hu;
  const float* __restrict__ sf = side ? vsf : usf;
  const float* __restrict__ W1 = side ? vW1 : uW1;
  const float* __restrict__ b1 = side ? vb1 : ub1;
  const float* __restrict__ W2 = side ? vW2 : uW2;
  float* __restrict__ o = out + (size_t)side * (NU * OUTD);

  __shared__ float s_sf[4][FDIM];
  __shared__ float s_h[4][MM];
  __shared__ float s_f[4][SIDE];
  const int t = threadIdx.x;
  const int r = t >> 6, s = t & 63;

  s_sf[r][s] = sf[(size_t)(u0 + r) * FDIM + s];
  s_sf[r][64 + s] = sf[(size_t)(u0 + r) * FDIM + 64 + s];
#pragma unroll
  for (int q = 0; q < 4; q++)
    s_h[r][q * 64 + s] = H[(size_t)(u0 + r) * MM + q * 64 + s];
  __syncthreads();

  float f = b1[s];
  for (int kk = 0; kk < FDIM; kk++) f += s_sf[r][kk] * W1[s * FDIM + kk];
  s_f[r][s] = f > 0.f ? f : 0.f;
  __syncthreads();

#pragma unroll
  for (int rep = 0; rep < 2; rep++) {
    const int oo = rep * 64 + s;
    if (oo < OUTD) {
      float a = 0.f;
      for (int kk = 0; kk < MM; kk++) a += s_h[r][kk] * dW[oo * MM + kk];
      for (int kk = 0; kk < SIDE; kk++) a += s_f[r][kk] * W2[oo * SIDE + kk];
      o[(size_t)(u0 + r) * OUTD + oo] = a > 0.f ? a : 0.f;
    }
  }
}

// ---------------------------------------------------------------------------
extern "C" void kernel_launch(void* const* d_in, const int* in_sizes, int n_in,
                              void* d_out, int out_size, void* d_ws, size_t ws_size,
                              hipStream_t stream) {
  const int* adj = (const int*)d_in[0];
  const float* usf = (const float*)d_in[1];
  const float* vsf = (const float*)d_in[2];
  const float* msgW = (const float*)d_in[3];
  const float* dW = (const float*)d_in[4];
  const float* uW1 = (const float*)d_in[5];
  const float* ub1 = (const float*)d_in[6];
  const float* uW2 = (const float*)d_in[7];
  const float* vW1 = (const float*)d_in[8];
  const float* vb1 = (const float*)d_in[9];
  const float* vW2 = (const float*)d_in[10];
  float* out = (float*)d_out;

  // workspace layout (all 256B-aligned)
  char* w = (char*)d_ws;
  const size_t A_BYTES = (size_t)MPAD * 4000;          // 16,128,000
  const size_t P_ELEMS = (size_t)RR * MM * 4000;       // 5,120,000
  const size_t H_ELEMS = (size_t)4000 * MM;            // 1,024,000
  int* Nu = (int*)w;                                   // 16384 B
  int* Nv = (int*)(w + 16384);                         // 16384 B
  int8_t* Au = (int8_t*)(w + 32768);
  int8_t* Av = Au + A_BYTES;
  __hip_bfloat16* Pu = (__hip_bfloat16*)(w + 32768 + 2 * A_BYTES);
  __hip_bfloat16* Pv = Pu + P_ELEMS;
  float* Hu = (float*)((char*)(Pv + P_ELEMS));
  float* Hv = Hu + H_ELEMS;
  const size_t need = 32768 + 2 * A_BYTES + 2 * P_ELEMS * 2 + 2 * H_ELEMS * 4;
  if (ws_size < need) return;  // fail visibly rather than corrupt

  hipMemsetAsync(w, 0, 32768, stream);
  k_trans<<<dim3(63, 63), 256, 0, stream>>>(adj, Au, Av, Nu, Nv);
  k_pbuild<<<1280, 256, 0, stream>>>(msgW, Nu, Nv, Pu, Pv);
  k_gemm<<<252, 256, 0, stream>>>(Au, Av, Pu, Pv, Nu, Nv, Hu, Hv);
  k_out<<<2000, 256, 0, stream>>>(Hu, Hv, usf, vsf, dW, uW1, ub1, uW2, vW1, vb1,
                                  vW2, out);
}

// Round 2
// 171.212 us; speedup vs baseline: 2.5601x; 2.5601x over previous
//
#include <hip/hip_runtime.h>
#include <hip/hip_bf16.h>
#include <hip/hip_fp8.h>
#include <stdint.h>

// Problem constants
#define NU 4000
#define NI 4000
#define RR 5
#define MM 256
#define OUTD 75
#define SIDE 64
#define FDIM 128
#define MPAD 4032           // 63 * 64

typedef float f32x4 __attribute__((ext_vector_type(4)));
typedef short bf16x8 __attribute__((ext_vector_type(8)));

static __device__ __forceinline__ short f2b(float x) {
  __hip_bfloat16 h = __float2bfloat16(x);
  return (short)__builtin_bit_cast(unsigned short, h);
}
static __device__ __forceinline__ float b2f(short x) {
  unsigned int u = ((unsigned int)(unsigned short)x) << 16;
  return __builtin_bit_cast(float, u);
}
static __device__ __forceinline__ bf16x8 cvt8(f32x4 a, f32x4 b) {
  bf16x8 r;
  r[0] = f2b(a[0]); r[1] = f2b(a[1]); r[2] = f2b(a[2]); r[3] = f2b(a[3]);
  r[4] = f2b(b[0]); r[5] = f2b(b[1]); r[6] = f2b(b[2]); r[7] = f2b(b[3]);
  return r;
}

// ---------------------------------------------------------------------------
// K1: adj->int8 (both layouts) + degree counts. (proven in round 1, unchanged)
// ---------------------------------------------------------------------------
__global__ __launch_bounds__(256) void k_trans(const int* __restrict__ adj,
                                               int8_t* __restrict__ a8,
                                               int8_t* __restrict__ a8t,
                                               int* __restrict__ Nu,
                                               int* __restrict__ Nv) {
  __shared__ int8_t lt[64][65];
  __shared__ int rowc[64];
  __shared__ int colp[4][64];
  const int i0 = blockIdx.x * 64;
  const int u0 = blockIdx.y * 64;
  const int t = threadIdx.x;
  const int w = t >> 6, lane = t & 63;
  int mycol = 0;
  for (int rep = 0; rep < 16; rep++) {
    const int r = rep * 4 + w;
    const int u = u0 + r, i = i0 + lane;
    int a = (u < NU && i < NI) ? adj[(size_t)u * NI + i] : 0;
    const int nz = (a > 0) ? 1 : 0;
    unsigned long long bal = __ballot(nz);
    if (lane == 0) rowc[r] = (int)__popcll(bal);
    mycol += nz;
    if (i < NI) a8[(size_t)u * NI + i] = (int8_t)a;
    lt[lane][r] = (int8_t)a;
  }
  colp[w][lane] = mycol;
  __syncthreads();
  for (int rep = 0; rep < 16; rep++) {
    const int r = rep * 4 + w;
    const int it = i0 + r, uu = u0 + lane;
    if (uu < NU) a8t[(size_t)it * NU + uu] = lt[r][lane];
  }
  if (t < 64) {
    const int cc = colp[0][t] + colp[1][t] + colp[2][t] + colp[3][t];
    if (i0 + t < NI && cc) atomicAdd(&Nv[i0 + t], cc);
    if (u0 + t < NU && rowc[t]) atomicAdd(&Nu[u0 + t], rowc[t]);
  }
}

// ---------------------------------------------------------------------------
// K2: P build (fp8 e4m3, x256 scale).
//   Pu[r*256+m][i] = e4m3(msg_W[r][m][NU+i] * rsqrt(Nv[i]) * 256)
//   Pv[r*256+m][u] = e4m3(msg_W[r][m][u]    * rsqrt(Nu[u]) * 256)
// ---------------------------------------------------------------------------
__global__ __launch_bounds__(256) void k_pbuild(const float* __restrict__ msgW,
                                                const int* __restrict__ Nu,
                                                const int* __restrict__ Nv,
                                                uint8_t* __restrict__ Pu,
                                                uint8_t* __restrict__ Pv) {
  const int b = blockIdx.x;                 // r*256 + m
  const float* src = msgW + (size_t)b * (NU + NI);
  for (int idx = threadIdx.x; idx < NU; idx += 256) {
    const int cu = Nu[idx], cv = Nv[idx];
    const float su = cu > 0 ? rsqrtf((float)cu) * 256.0f : 0.f;
    const float sv = cv > 0 ? rsqrtf((float)cv) * 256.0f : 0.f;
    __hip_fp8_e4m3 pv(src[idx] * su);
    __hip_fp8_e4m3 pu(src[NU + idx] * sv);
    Pv[(size_t)b * NU + idx] = __builtin_bit_cast(uint8_t, pv);
    Pu[(size_t)b * NI + idx] = __builtin_bit_cast(uint8_t, pu);
  }
}

// ---------------------------------------------------------------------------
// K3: one-hot fp8 MFMA GEMM, LDS-staged B, K-split x4, partial bf16 out.
// BM=64, BN=256(full), BK=32. 512 thr = 8 waves, wave = 64 rows x 32 cols.
// grid 504: bid&7 -> (side, ks) [XCD-grouped], bid>>3 -> bm (0..62).
// ---------------------------------------------------------------------------
#define GLOAD_LDS(g, s) __builtin_amdgcn_global_load_lds( \
    (const __attribute__((address_space(1))) uint32_t*)(g), \
    (__attribute__((address_space(3))) uint32_t*)(s), 16, 0, 0)

#define MFMA8(A_, B_, C_) \
  __builtin_amdgcn_mfma_f32_16x16x32_fp8_fp8((long)(A_), (long)(B_), (C_), 0, 0, 0)

static __device__ __forceinline__ unsigned long long oh64(uint2 a, int r) {
  // one-hot via byte-table perm: sel byte = adj value (0..5) picks table byte.
  // table[a] = 0x38 (fp8 1.0) iff a == r+1. sel<4 -> arg1(TL), sel>=4 -> arg0(TH).
  const uint32_t TL[5] = {0x00003800u, 0x00380000u, 0x38000000u, 0u, 0u};
  const uint32_t TH[5] = {0u, 0u, 0u, 0x00000038u, 0x00003800u};
  uint32_t lo = __builtin_amdgcn_perm(TH[r], TL[r], a.x);
  uint32_t hi = __builtin_amdgcn_perm(TH[r], TL[r], a.y);
  return (((unsigned long long)hi) << 32) | lo;
}

__global__ __launch_bounds__(512) void k_gemm(const uint8_t* __restrict__ Au,
                                              const uint8_t* __restrict__ Av,
                                              const uint8_t* __restrict__ Pu,
                                              const uint8_t* __restrict__ Pv,
                                              __hip_bfloat16* __restrict__ Hp) {
  __shared__ __attribute__((aligned(16))) char Bls[2][40960];

  const int bid = blockIdx.x;
  const int g3 = bid & 7;
  const int side = g3 & 1;
  const int ks = g3 >> 1;            // 0..3
  const int bm = bid >> 3;           // 0..62
  const uint8_t* __restrict__ A8 = side ? Av : Au;
  const uint8_t* __restrict__ P = side ? Pv : Pu;

  const int kbeg = ks * 1024;
  const int kend = (ks == 3) ? 4000 : (kbeg + 1024);

  const int t = threadIdx.x;
  const int w = t >> 6, l = t & 63;
  const int l15 = l & 15, l4 = l >> 4;

  // A pointer: row = bm*64 + g*16 + l15, k-offset 8*l4
  const uint8_t* pa = A8 + (size_t)(bm * 64 + l15) * 4000 + 8 * l4;

  // LDS read addr (c=0): col = w*32 + l15; slot swizzle s(col) in {0,2}
  const int col = w * 32 + l15;
  const int s0 = ((col ^ (col >> 2)) & 1) << 1;
  const int ad0 = col * 32 + ((l4 ^ s0) << 3);
  // c=1: col+16 -> same swizzle -> +512 bytes

  // staging offsets: 5 global_load_lds per wave
  uint32_t soff[5]; uint32_t ldst[5];
#pragma unroll
  for (int i = 0; i < 5; ++i) {
    const int n = w * 5 + i;
    const int rr = n >> 3;
    const int scol = (n & 7) * 32 + (l >> 1);
    const int ss = ((scol ^ (scol >> 2)) & 1) << 1;
    soff[i] = (uint32_t)((rr * 256 + scol) * 4000) + ((((l & 1) << 1) ^ ss) << 3);
    ldst[i] = (uint32_t)(n << 10);
  }

#define STAGE(bi, kk) { _Pragma("unroll") \
  for (int i_ = 0; i_ < 5; ++i_) \
    GLOAD_LDS(P + soff[i_] + (kk), &Bls[bi][0] + ldst[i_]); }

  f32x4 acc[4][2] = {};

  STAGE(0, kbeg);
  __syncthreads();
  int cur = 0;
  for (int kk = kbeg; kk < kend; kk += 32) {
    if (kk + 32 < kend) STAGE(cur ^ 1, kk + 32);
    const char* lb = &Bls[cur][0];
    const uint2 av0 = *(const uint2*)(pa + kk);
    const uint2 av1 = *(const uint2*)(pa + 64000 + kk);
    const uint2 av2 = *(const uint2*)(pa + 128000 + kk);
    const uint2 av3 = *(const uint2*)(pa + 192000 + kk);
#pragma unroll
    for (int r = 0; r < 5; ++r) {
      const unsigned long long b0 = *(const unsigned long long*)(lb + r * 8192 + ad0);
      const unsigned long long b1 = *(const unsigned long long*)(lb + r * 8192 + ad0 + 512);
      const unsigned long long A0 = oh64(av0, r);
      const unsigned long long A1 = oh64(av1, r);
      const unsigned long long A2 = oh64(av2, r);
      const unsigned long long A3 = oh64(av3, r);
      acc[0][0] = MFMA8(A0, b0, acc[0][0]); acc[0][1] = MFMA8(A0, b1, acc[0][1]);
      acc[1][0] = MFMA8(A1, b0, acc[1][0]); acc[1][1] = MFMA8(A1, b1, acc[1][1]);
      acc[2][0] = MFMA8(A2, b0, acc[2][0]); acc[2][1] = MFMA8(A2, b1, acc[2][1]);
      acc[3][0] = MFMA8(A3, b0, acc[3][0]); acc[3][1] = MFMA8(A3, b1, acc[3][1]);
    }
    __syncthreads();
    cur ^= 1;
  }

  // epilogue: store raw bf16 partials (scale+relu deferred to k_out)
  __hip_bfloat16* hp = Hp + (size_t)(ks * 2 + side) * (4000 * 256);
#pragma unroll
  for (int gg = 0; gg < 4; ++gg) {
#pragma unroll
    for (int c = 0; c < 2; ++c) {
      const int ocol = w * 32 + c * 16 + l15;
      const int rowb = bm * 64 + gg * 16 + l4 * 4;
#pragma unroll
      for (int reg = 0; reg < 4; ++reg) {
        const int orow = rowb + reg;
        if (orow < 4000)
          hp[(size_t)orow * 256 + ocol] = __float2bfloat16(acc[gg][c][reg]);
      }
    }
  }
#undef STAGE
}

// ---------------------------------------------------------------------------
// K4: fused stage 2 (MFMA). Per block: 32 rows (2 waves x 16 rows).
//   F = relu(sf@W1^T + b1)           (K=128, bf16 MFMA)
//   out = relu(Hsum@dW^T + F@W2^T)   (K=256 + K=64), Hsum = relu(sc*SUM Hp)
// grid 250 = 2 sides x 125, block 128.
// ---------------------------------------------------------------------------
__global__ __launch_bounds__(128) void k_out(const __hip_bfloat16* __restrict__ Hp,
                                             const float* __restrict__ usf,
                                             const float* __restrict__ vsf,
                                             const float* __restrict__ dW,
                                             const float* __restrict__ uW1,
                                             const float* __restrict__ ub1,
                                             const float* __restrict__ uW2,
                                             const float* __restrict__ vW1,
                                             const float* __restrict__ vb1,
                                             const float* __restrict__ vW2,
                                             const int* __restrict__ Nu,
                                             const int* __restrict__ Nv,
                                             float* __restrict__ out) {
  const int bid = blockIdx.x;
  const int side = bid / 125, rb = bid % 125;
  const int t = threadIdx.x, w = t >> 6, l = t & 63;
  const int l15 = l & 15, l4 = l >> 4;
  const int r0 = rb * 32 + w * 16;
  const float* __restrict__ sf = side ? vsf : usf;
  const float* __restrict__ W1 = side ? vW1 : uW1;
  const float* __restrict__ b1 = side ? vb1 : ub1;
  const float* __restrict__ W2 = side ? vW2 : uW2;
  const int* __restrict__ cnt = side ? Nv : Nu;
  const __hip_bfloat16* __restrict__ hp = Hp + (size_t)side * (4000 * 256);

  const int myrow = r0 + l15;
  float sc;
  { const int cv = cnt[myrow]; sc = cv > 0 ? rsqrtf((float)cv) * (1.0f / 256.0f) : 0.f; }

  __shared__ __hip_bfloat16 lf[2][16][72];

  // ---- Phase A: F = relu(sf @ W1^T + b1) ----
  f32x4 fA[4] = {};
#pragma unroll
  for (int kk = 0; kk < 128; kk += 32) {
    const float* ps = sf + (size_t)myrow * 128 + kk + 8 * l4;
    const bf16x8 af = cvt8(*(const f32x4*)ps, *(const f32x4*)(ps + 4));
#pragma unroll
    for (int c = 0; c < 4; ++c) {
      const float* pw = W1 + (size_t)(c * 16 + l15) * 128 + kk + 8 * l4;
      const bf16x8 bf = cvt8(*(const f32x4*)pw, *(const f32x4*)(pw + 4));
      fA[c] = __builtin_amdgcn_mfma_f32_16x16x32_bf16(af, bf, fA[c], 0, 0, 0);
    }
  }
#pragma unroll
  for (int c = 0; c < 4; ++c) {
    const float bv = b1[c * 16 + l15];
#pragma unroll
    for (int reg = 0; reg < 4; ++reg) {
      float v = fA[c][reg] + bv;
      lf[w][l4 * 4 + reg][c * 16 + l15] = __float2bfloat16(v > 0.f ? v : 0.f);
    }
  }
  __syncthreads();

  // ---- Phase B: out = relu(Hsum@dW^T + F@W2^T) ----
  f32x4 oA[5] = {};
  const __hip_bfloat16* hbase = hp + (size_t)myrow * 256 + 8 * l4;
#pragma unroll
  for (int kk = 0; kk < 256; kk += 32) {
    const bf16x8 q0 = *(const bf16x8*)(hbase + kk);
    const bf16x8 q1 = *(const bf16x8*)(hbase + 2048000 + kk);
    const bf16x8 q2 = *(const bf16x8*)(hbase + 4096000 + kk);
    const bf16x8 q3 = *(const bf16x8*)(hbase + 6144000 + kk);
    bf16x8 af;
#pragma unroll
    for (int j = 0; j < 8; ++j) {
      float hv = b2f(q0[j]) + b2f(q1[j]) + b2f(q2[j]) + b2f(q3[j]);
      hv *= sc;
      af[j] = f2b(hv > 0.f ? hv : 0.f);
    }
#pragma unroll
    for (int c = 0; c < 5; ++c) {
      int oc = c * 16 + l15; if (oc > 74) oc = 74;   // clamp, stores guarded
      const float* pd = dW + (size_t)oc * 256 + kk + 8 * l4;
      const bf16x8 bf = cvt8(*(const f32x4*)pd, *(const f32x4*)(pd + 4));
      oA[c] = __builtin_amdgcn_mfma_f32_16x16x32_bf16(af, bf, oA[c], 0, 0, 0);
    }
  }
#pragma unroll
  for (int kk = 0; kk < 64; kk += 32) {
    const bf16x8 af = *(const bf16x8*)(&lf[w][l15][kk + 8 * l4]);
#pragma unroll
    for (int c = 0; c < 5; ++c) {
      int oc = c * 16 + l15; if (oc > 74) oc = 74;
      const float* pw = W2 + (size_t)oc * 64 + kk + 8 * l4;
      const bf16x8 bf = cvt8(*(const f32x4*)pw, *(const f32x4*)(pw + 4));
      oA[c] = __builtin_amdgcn_mfma_f32_16x16x32_bf16(af, bf, oA[c], 0, 0, 0);
    }
  }
  float* po = out + (size_t)side * (4000 * 75);
#pragma unroll
  for (int c = 0; c < 5; ++c) {
    const int oc = c * 16 + l15;
    if (oc < 75) {
#pragma unroll
      for (int reg = 0; reg < 4; ++reg) {
        const int orow = r0 + l4 * 4 + reg;
        const float v = oA[c][reg];
        po[(size_t)orow * 75 + oc] = v > 0.f ? v : 0.f;
      }
    }
  }
}

// ---------------------------------------------------------------------------
extern "C" void kernel_launch(void* const* d_in, const int* in_sizes, int n_in,
                              void* d_out, int out_size, void* d_ws, size_t ws_size,
                              hipStream_t stream) {
  const int* adj = (const int*)d_in[0];
  const float* usf = (const float*)d_in[1];
  const float* vsf = (const float*)d_in[2];
  const float* msgW = (const float*)d_in[3];
  const float* dW = (const float*)d_in[4];
  const float* uW1 = (const float*)d_in[5];
  const float* ub1 = (const float*)d_in[6];
  const float* uW2 = (const float*)d_in[7];
  const float* vW1 = (const float*)d_in[8];
  const float* vb1 = (const float*)d_in[9];
  const float* vW2 = (const float*)d_in[10];
  float* out = (float*)d_out;

  char* w = (char*)d_ws;
  const size_t A_BYTES = (size_t)MPAD * 4000;          // 16,128,000
  const size_t P_BYTES = (size_t)RR * MM * 4000;       // 5,120,000 (fp8)
  const size_t HP_BYTES = (size_t)8 * 4000 * 256 * 2;  // 16,384,000 (bf16, 4 splits x 2 sides)
  int* Nu = (int*)w;
  int* Nv = (int*)(w + 16384);
  int8_t* Au = (int8_t*)(w + 32768);
  int8_t* Av = Au + A_BYTES;
  uint8_t* Pu = (uint8_t*)(w + 32768 + 2 * A_BYTES);
  uint8_t* Pv = Pu + P_BYTES;
  __hip_bfloat16* Hp = (__hip_bfloat16*)(w + 32768 + 2 * A_BYTES + 2 * P_BYTES);
  const size_t need = 32768 + 2 * A_BYTES + 2 * P_BYTES + HP_BYTES;  // 58,912,768
  if (ws_size < need) return;

  hipMemsetAsync(w, 0, 32768, stream);
  k_trans<<<dim3(63, 63), 256, 0, stream>>>(adj, Au, Av, Nu, Nv);
  k_pbuild<<<1280, 256, 0, stream>>>(msgW, Nu, Nv, Pu, Pv);
  k_gemm<<<504, 512, 0, stream>>>((const uint8_t*)Au, (const uint8_t*)Av, Pu, Pv, Hp);
  k_out<<<250, 128, 0, stream>>>(Hp, usf, vsf, dW, uW1, ub1, uW2, vW1, vb1, vW2,
                                 Nu, Nv, out);
}

// Round 3
// 157.015 us; speedup vs baseline: 2.7916x; 1.0904x over previous
//
#include <hip/hip_runtime.h>
#include <hip/hip_bf16.h>
#include <hip/hip_fp8.h>
#include <stdint.h>

// Problem constants
#define NU 4000
#define NI 4000
#define RR 5
#define MM 256
#define OUTD 75
#define SIDE 64
#define FDIM 128
#define MPAD 4032           // 63 * 64

typedef float f32x4 __attribute__((ext_vector_type(4)));
typedef short bf16x8 __attribute__((ext_vector_type(8)));

static __device__ __forceinline__ short f2b(float x) {
  __hip_bfloat16 h = __float2bfloat16(x);
  return (short)__builtin_bit_cast(unsigned short, h);
}
static __device__ __forceinline__ float b2f(short x) {
  unsigned int u = ((unsigned int)(unsigned short)x) << 16;
  return __builtin_bit_cast(float, u);
}
static __device__ __forceinline__ bf16x8 cvt8(f32x4 a, f32x4 b) {
  bf16x8 r;
  r[0] = f2b(a[0]); r[1] = f2b(a[1]); r[2] = f2b(a[2]); r[3] = f2b(a[3]);
  r[4] = f2b(b[0]); r[5] = f2b(b[1]); r[6] = f2b(b[2]); r[7] = f2b(b[3]);
  return r;
}

// ---------------------------------------------------------------------------
// K1: adj->int8 (both layouts) + degree counts. (proven, unchanged)
// ---------------------------------------------------------------------------
__global__ __launch_bounds__(256) void k_trans(const int* __restrict__ adj,
                                               int8_t* __restrict__ a8,
                                               int8_t* __restrict__ a8t,
                                               int* __restrict__ Nu,
                                               int* __restrict__ Nv) {
  __shared__ int8_t lt[64][65];
  __shared__ int rowc[64];
  __shared__ int colp[4][64];
  const int i0 = blockIdx.x * 64;
  const int u0 = blockIdx.y * 64;
  const int t = threadIdx.x;
  const int w = t >> 6, lane = t & 63;
  int mycol = 0;
  for (int rep = 0; rep < 16; rep++) {
    const int r = rep * 4 + w;
    const int u = u0 + r, i = i0 + lane;
    int a = (u < NU && i < NI) ? adj[(size_t)u * NI + i] : 0;
    const int nz = (a > 0) ? 1 : 0;
    unsigned long long bal = __ballot(nz);
    if (lane == 0) rowc[r] = (int)__popcll(bal);
    mycol += nz;
    if (i < NI) a8[(size_t)u * NI + i] = (int8_t)a;
    lt[lane][r] = (int8_t)a;
  }
  colp[w][lane] = mycol;
  __syncthreads();
  for (int rep = 0; rep < 16; rep++) {
    const int r = rep * 4 + w;
    const int it = i0 + r, uu = u0 + lane;
    if (uu < NU) a8t[(size_t)it * NU + uu] = lt[r][lane];
  }
  if (t < 64) {
    const int cc = colp[0][t] + colp[1][t] + colp[2][t] + colp[3][t];
    if (i0 + t < NI && cc) atomicAdd(&Nv[i0 + t], cc);
    if (u0 + t < NU && rowc[t]) atomicAdd(&Nu[u0 + t], rowc[t]);
  }
}

// ---------------------------------------------------------------------------
// K2: P build (fp8 e4m3, x256 scale). (proven, unchanged)
// ---------------------------------------------------------------------------
__global__ __launch_bounds__(256) void k_pbuild(const float* __restrict__ msgW,
                                                const int* __restrict__ Nu,
                                                const int* __restrict__ Nv,
                                                uint8_t* __restrict__ Pu,
                                                uint8_t* __restrict__ Pv) {
  const int b = blockIdx.x;                 // r*256 + m
  const float* src = msgW + (size_t)b * (NU + NI);
  for (int idx = threadIdx.x; idx < NU; idx += 256) {
    const int cu = Nu[idx], cv = Nv[idx];
    const float su = cu > 0 ? rsqrtf((float)cu) * 256.0f : 0.f;
    const float sv = cv > 0 ? rsqrtf((float)cv) * 256.0f : 0.f;
    __hip_fp8_e4m3 pv(src[idx] * su);
    __hip_fp8_e4m3 pu(src[NU + idx] * sv);
    Pv[(size_t)b * NU + idx] = __builtin_bit_cast(uint8_t, pv);
    Pu[(size_t)b * NI + idx] = __builtin_bit_cast(uint8_t, pu);
  }
}

// ---------------------------------------------------------------------------
// K3: one-hot fp8 MFMA GEMM.
//   vs R2: 2g x 4c wave geometry (wave = 32 rows x 64 cols), A register
//   double-buffer prefetch, counted vmcnt(2) + raw s_barrier (no full drain),
//   setprio around MFMA cluster.
// BM=64, BN=256, BK=32. 512 thr = 8 waves. grid 504: bid&7 -> (side,ks).
// ---------------------------------------------------------------------------
#define GLOAD_LDS(g, s) __builtin_amdgcn_global_load_lds( \
    (const __attribute__((address_space(1))) uint32_t*)(g), \
    (__attribute__((address_space(3))) uint32_t*)(s), 16, 0, 0)

#define MFMA8(A_, B_, C_) \
  __builtin_amdgcn_mfma_f32_16x16x32_fp8_fp8((long)(A_), (long)(B_), (C_), 0, 0, 0)

static __device__ __forceinline__ unsigned long long oh64(uint2 a, int r) {
  // one-hot via byte-table perm: sel byte = adj value (0..5) picks table byte.
  // table[v] = 0x38 (fp8 1.0) iff v == r+1. sel<4 -> arg1(TL), sel>=4 -> arg0(TH).
  const uint32_t TL[5] = {0x00003800u, 0x00380000u, 0x38000000u, 0u, 0u};
  const uint32_t TH[5] = {0u, 0u, 0u, 0x00000038u, 0x00003800u};
  uint32_t lo = __builtin_amdgcn_perm(TH[r], TL[r], a.x);
  uint32_t hi = __builtin_amdgcn_perm(TH[r], TL[r], a.y);
  return (((unsigned long long)hi) << 32) | lo;
}

__global__ __launch_bounds__(512, 4) void k_gemm(const uint8_t* __restrict__ Au,
                                                 const uint8_t* __restrict__ Av,
                                                 const uint8_t* __restrict__ Pu,
                                                 const uint8_t* __restrict__ Pv,
                                                 __hip_bfloat16* __restrict__ Hp) {
  __shared__ __attribute__((aligned(16))) char Bls[2][40960];

  const int bid = blockIdx.x;
  const int g3 = bid & 7;
  const int side = g3 & 1;
  const int ks = g3 >> 1;            // 0..3
  const int bm = bid >> 3;           // 0..62
  const uint8_t* __restrict__ A8 = side ? Av : Au;
  const uint8_t* __restrict__ P = side ? Pv : Pu;

  const int kbeg = ks * 1024;
  const int kend = (ks == 3) ? 4000 : (kbeg + 1024);

  const int t = threadIdx.x;
  const int w = t >> 6, l = t & 63;
  const int l15 = l & 15, l4 = l >> 4;
  const int wr = w & 1, wc = w >> 1;     // wave = 32 rows x 64 cols

  // A pointer: row = bm*64 + wr*32 + g*16 + l15, k-offset 8*l4
  const uint8_t* pa = A8 + (size_t)(bm * 64 + wr * 32 + l15) * 4000 + 8 * l4;

  // LDS read base (r=0,c=0): col = wc*64 + l15; slot swizzle s(col) in {0,2}
  // (adding c*16 flips neither bit0 nor bit2 of col -> same s across c)
  const int col0 = wc * 64 + l15;
  const int s0 = ((col0 ^ (col0 >> 2)) & 1) << 1;
  const int ad0 = col0 * 32 + ((l4 ^ s0) << 3);
  // addr(r,c) = r*8192 + c*512 + ad0

  // staging offsets: 5 global_load_lds per wave (verified mapping from R1)
  uint32_t soff[5]; uint32_t ldst[5];
#pragma unroll
  for (int i = 0; i < 5; ++i) {
    const int n = w * 5 + i;
    const int rr = n >> 3;
    const int scol = (n & 7) * 32 + (l >> 1);
    const int ss = ((scol ^ (scol >> 2)) & 1) << 1;
    soff[i] = (uint32_t)((rr * 256 + scol) * 4000) + ((((l & 1) << 1) ^ ss) << 3);
    ldst[i] = (uint32_t)(n << 10);
  }

#define STAGE(bi, kk) { _Pragma("unroll") \
  for (int i_ = 0; i_ < 5; ++i_) \
    GLOAD_LDS(P + soff[i_] + (kk), &Bls[bi][0] + ldst[i_]); }

  f32x4 acc[2][4] = {};

  // prologue: stage buf0 + load A(kbeg); drain only the stage loads
  STAGE(0, kbeg);
  uint2 a0 = *(const uint2*)(pa + kbeg);
  uint2 a1 = *(const uint2*)(pa + 64000 + kbeg);
  asm volatile("s_waitcnt vmcnt(2)" ::: "memory");
  __builtin_amdgcn_s_barrier();

  int cur = 0;
  for (int kk = kbeg; kk < kend; kk += 32) {
    const bool more = (kk + 32 < kend);
    uint2 n0, n1;
    if (more) {
      STAGE(cur ^ 1, kk + 32);                       // 5 gload_lds
      n0 = *(const uint2*)(pa + kk + 32);            // A prefetch (2 loads)
      n1 = *(const uint2*)(pa + 64000 + kk + 32);
    }
    const char* lb = &Bls[cur][0];
    __builtin_amdgcn_s_setprio(1);
#pragma unroll
    for (int r = 0; r < 5; ++r) {
      const unsigned long long b0 = *(const unsigned long long*)(lb + r * 8192 + ad0);
      const unsigned long long b1 = *(const unsigned long long*)(lb + r * 8192 + ad0 + 512);
      const unsigned long long b2 = *(const unsigned long long*)(lb + r * 8192 + ad0 + 1024);
      const unsigned long long b3 = *(const unsigned long long*)(lb + r * 8192 + ad0 + 1536);
      const unsigned long long A0 = oh64(a0, r);
      const unsigned long long A1 = oh64(a1, r);
      acc[0][0] = MFMA8(A0, b0, acc[0][0]);
      acc[0][1] = MFMA8(A0, b1, acc[0][1]);
      acc[0][2] = MFMA8(A0, b2, acc[0][2]);
      acc[0][3] = MFMA8(A0, b3, acc[0][3]);
      acc[1][0] = MFMA8(A1, b0, acc[1][0]);
      acc[1][1] = MFMA8(A1, b1, acc[1][1]);
      acc[1][2] = MFMA8(A1, b2, acc[1][2]);
      acc[1][3] = MFMA8(A1, b3, acc[1][3]);
    }
    __builtin_amdgcn_s_setprio(0);
    if (more) { a0 = n0; a1 = n1; }
    // drain the 5 stage loads; leave the 2 A-prefetches in flight
    asm volatile("s_waitcnt vmcnt(2)" ::: "memory");
    __builtin_amdgcn_s_barrier();
    cur ^= 1;
  }

  // epilogue: store raw bf16 partials (scale+relu deferred to k_out)
  __hip_bfloat16* hp = Hp + (size_t)(ks * 2 + side) * (4000 * 256);
#pragma unroll
  for (int gg = 0; gg < 2; ++gg) {
    const int rowb = bm * 64 + wr * 32 + gg * 16 + l4 * 4;
#pragma unroll
    for (int c = 0; c < 4; ++c) {
      const int ocol = wc * 64 + c * 16 + l15;
#pragma unroll
      for (int reg = 0; reg < 4; ++reg) {
        const int orow = rowb + reg;
        if (orow < 4000)
          hp[(size_t)orow * 256 + ocol] = __float2bfloat16(acc[gg][c][reg]);
      }
    }
  }
#undef STAGE
}

// ---------------------------------------------------------------------------
// K4: fused stage 2 (MFMA). (proven, unchanged)
// ---------------------------------------------------------------------------
__global__ __launch_bounds__(128) void k_out(const __hip_bfloat16* __restrict__ Hp,
                                             const float* __restrict__ usf,
                                             const float* __restrict__ vsf,
                                             const float* __restrict__ dW,
                                             const float* __restrict__ uW1,
                                             const float* __restrict__ ub1,
                                             const float* __restrict__ uW2,
                                             const float* __restrict__ vW1,
                                             const float* __restrict__ vb1,
                                             const float* __restrict__ vW2,
                                             const int* __restrict__ Nu,
                                             const int* __restrict__ Nv,
                                             float* __restrict__ out) {
  const int bid = blockIdx.x;
  const int side = bid / 125, rb = bid % 125;
  const int t = threadIdx.x, w = t >> 6, l = t & 63;
  const int l15 = l & 15, l4 = l >> 4;
  const int r0 = rb * 32 + w * 16;
  const float* __restrict__ sf = side ? vsf : usf;
  const float* __restrict__ W1 = side ? vW1 : uW1;
  const float* __restrict__ b1 = side ? vb1 : ub1;
  const float* __restrict__ W2 = side ? vW2 : uW2;
  const int* __restrict__ cnt = side ? Nv : Nu;
  const __hip_bfloat16* __restrict__ hp = Hp + (size_t)side * (4000 * 256);

  const int myrow = r0 + l15;
  float sc;
  { const int cv = cnt[myrow]; sc = cv > 0 ? rsqrtf((float)cv) * (1.0f / 256.0f) : 0.f; }

  __shared__ __hip_bfloat16 lf[2][16][72];

  // ---- Phase A: F = relu(sf @ W1^T + b1) ----
  f32x4 fA[4] = {};
#pragma unroll
  for (int kk = 0; kk < 128; kk += 32) {
    const float* ps = sf + (size_t)myrow * 128 + kk + 8 * l4;
    const bf16x8 af = cvt8(*(const f32x4*)ps, *(const f32x4*)(ps + 4));
#pragma unroll
    for (int c = 0; c < 4; ++c) {
      const float* pw = W1 + (size_t)(c * 16 + l15) * 128 + kk + 8 * l4;
      const bf16x8 bf = cvt8(*(const f32x4*)pw, *(const f32x4*)(pw + 4));
      fA[c] = __builtin_amdgcn_mfma_f32_16x16x32_bf16(af, bf, fA[c], 0, 0, 0);
    }
  }
#pragma unroll
  for (int c = 0; c < 4; ++c) {
    const float bv = b1[c * 16 + l15];
#pragma unroll
    for (int reg = 0; reg < 4; ++reg) {
      float v = fA[c][reg] + bv;
      lf[w][l4 * 4 + reg][c * 16 + l15] = __float2bfloat16(v > 0.f ? v : 0.f);
    }
  }
  __syncthreads();

  // ---- Phase B: out = relu(Hsum@dW^T + F@W2^T) ----
  f32x4 oA[5] = {};
  const __hip_bfloat16* hbase = hp + (size_t)myrow * 256 + 8 * l4;
#pragma unroll
  for (int kk = 0; kk < 256; kk += 32) {
    const bf16x8 q0 = *(const bf16x8*)(hbase + kk);
    const bf16x8 q1 = *(const bf16x8*)(hbase + 2048000 + kk);
    const bf16x8 q2 = *(const bf16x8*)(hbase + 4096000 + kk);
    const bf16x8 q3 = *(const bf16x8*)(hbase + 6144000 + kk);
    bf16x8 af;
#pragma unroll
    for (int j = 0; j < 8; ++j) {
      float hv = b2f(q0[j]) + b2f(q1[j]) + b2f(q2[j]) + b2f(q3[j]);
      hv *= sc;
      af[j] = f2b(hv > 0.f ? hv : 0.f);
    }
#pragma unroll
    for (int c = 0; c < 5; ++c) {
      int oc = c * 16 + l15; if (oc > 74) oc = 74;   // clamp, stores guarded
      const float* pd = dW + (size_t)oc * 256 + kk + 8 * l4;
      const bf16x8 bf = cvt8(*(const f32x4*)pd, *(const f32x4*)(pd + 4));
      oA[c] = __builtin_amdgcn_mfma_f32_16x16x32_bf16(af, bf, oA[c], 0, 0, 0);
    }
  }
#pragma unroll
  for (int kk = 0; kk < 64; kk += 32) {
    const bf16x8 af = *(const bf16x8*)(&lf[w][l15][kk + 8 * l4]);
#pragma unroll
    for (int c = 0; c < 5; ++c) {
      int oc = c * 16 + l15; if (oc > 74) oc = 74;
      const float* pw = W2 + (size_t)oc * 64 + kk + 8 * l4;
      const bf16x8 bf = cvt8(*(const f32x4*)pw, *(const f32x4*)(pw + 4));
      oA[c] = __builtin_amdgcn_mfma_f32_16x16x32_bf16(af, bf, oA[c], 0, 0, 0);
    }
  }
  float* po = out + (size_t)side * (4000 * 75);
#pragma unroll
  for (int c = 0; c < 5; ++c) {
    const int oc = c * 16 + l15;
    if (oc < 75) {
#pragma unroll
      for (int reg = 0; reg < 4; ++reg) {
        const int orow = r0 + l4 * 4 + reg;
        const float v = oA[c][reg];
        po[(size_t)orow * 75 + oc] = v > 0.f ? v : 0.f;
      }
    }
  }
}

// ---------------------------------------------------------------------------
extern "C" void kernel_launch(void* const* d_in, const int* in_sizes, int n_in,
                              void* d_out, int out_size, void* d_ws, size_t ws_size,
                              hipStream_t stream) {
  const int* adj = (const int*)d_in[0];
  const float* usf = (const float*)d_in[1];
  const float* vsf = (const float*)d_in[2];
  const float* msgW = (const float*)d_in[3];
  const float* dW = (const float*)d_in[4];
  const float* uW1 = (const float*)d_in[5];
  const float* ub1 = (const float*)d_in[6];
  const float* uW2 = (const float*)d_in[7];
  const float* vW1 = (const float*)d_in[8];
  const float* vb1 = (const float*)d_in[9];
  const float* vW2 = (const float*)d_in[10];
  float* out = (float*)d_out;

  char* w = (char*)d_ws;
  const size_t A_BYTES = (size_t)MPAD * 4000;          // 16,128,000
  const size_t P_BYTES = (size_t)RR * MM * 4000;       // 5,120,000 (fp8)
  const size_t HP_BYTES = (size_t)8 * 4000 * 256 * 2;  // 16,384,000 (bf16)
  int* Nu = (int*)w;
  int* Nv = (int*)(w + 16384);
  int8_t* Au = (int8_t*)(w + 32768);
  int8_t* Av = Au + A_BYTES;
  uint8_t* Pu = (uint8_t*)(w + 32768 + 2 * A_BYTES);
  uint8_t* Pv = Pu + P_BYTES;
  __hip_bfloat16* Hp = (__hip_bfloat16*)(w + 32768 + 2 * A_BYTES + 2 * P_BYTES);
  const size_t need = 32768 + 2 * A_BYTES + 2 * P_BYTES + HP_BYTES;  // 58,912,768
  if (ws_size < need) return;

  hipMemsetAsync(w, 0, 32768, stream);
  k_trans<<<dim3(63, 63), 256, 0, stream>>>(adj, Au, Av, Nu, Nv);
  k_pbuild<<<1280, 256, 0, stream>>>(msgW, Nu, Nv, Pu, Pv);
  k_gemm<<<504, 512, 0, stream>>>((const uint8_t*)Au, (const uint8_t*)Av, Pu, Pv, Hp);
  k_out<<<250, 128, 0, stream>>>(Hp, usf, vsf, dW, uW1, ub1, uW2, vW1, vb1, vW2,
                                 Nu, Nv, out);
}

// Round 4
// 115.213 us; speedup vs baseline: 3.8044x; 1.3628x over previous
//
#include <hip/hip_runtime.h>
#include <hip/hip_bf16.h>
#include <stdint.h>

// Problem constants
#define NU 4000
#define NI 4000
#define RR 5
#define MM 256
#define OUTD 75
#define FDIM 128
#define KP 4032                 // padded K/row length (63*64)
#define HP_STRIDE 1024000       // 4000*256 elements per partial

typedef float f32x4 __attribute__((ext_vector_type(4)));
typedef int   i32x4 __attribute__((ext_vector_type(4)));
typedef short bf16x8 __attribute__((ext_vector_type(8)));

static __device__ __forceinline__ short f2b(float x) {
  __hip_bfloat16 h = __float2bfloat16(x);
  return (short)__builtin_bit_cast(unsigned short, h);
}
static __device__ __forceinline__ float b2f(short x) {
  unsigned int u = ((unsigned int)(unsigned short)x) << 16;
  return __builtin_bit_cast(float, u);
}
static __device__ __forceinline__ bf16x8 cvt8(f32x4 a, f32x4 b) {
  bf16x8 r;
  r[0] = f2b(a[0]); r[1] = f2b(a[1]); r[2] = f2b(a[2]); r[3] = f2b(a[3]);
  r[4] = f2b(b[0]); r[5] = f2b(b[1]); r[6] = f2b(b[2]); r[7] = f2b(b[3]);
  return r;
}

// ---------------------------------------------------------------------------
// K1: adj->int8 (both layouts, KP-padded with zeros) + degree counts.
// ---------------------------------------------------------------------------
__global__ __launch_bounds__(256) void k_trans(const int* __restrict__ adj,
                                               int8_t* __restrict__ a8,
                                               int8_t* __restrict__ a8t,
                                               int* __restrict__ Nu,
                                               int* __restrict__ Nv) {
  __shared__ int8_t lt[64][65];
  __shared__ int rowc[64];
  __shared__ int colp[4][64];
  const int i0 = blockIdx.x * 64;
  const int u0 = blockIdx.y * 64;
  const int t = threadIdx.x;
  const int w = t >> 6, lane = t & 63;
  int mycol = 0;
  for (int rep = 0; rep < 16; rep++) {
    const int r = rep * 4 + w;
    const int u = u0 + r, i = i0 + lane;
    int a = (u < NU && i < NI) ? adj[(size_t)u * NI + i] : 0;
    const int nz = (a > 0) ? 1 : 0;
    unsigned long long bal = __ballot(nz);
    if (lane == 0) rowc[r] = (int)__popcll(bal);
    mycol += nz;
    a8[(size_t)u * KP + i] = (int8_t)a;       // rows/cols padded with 0
    lt[lane][r] = (int8_t)a;
  }
  colp[w][lane] = mycol;
  __syncthreads();
  for (int rep = 0; rep < 16; rep++) {
    const int r = rep * 4 + w;
    a8t[(size_t)(i0 + r) * KP + (u0 + lane)] = lt[r][lane];
  }
  if (t < 64) {
    const int cc = colp[0][t] + colp[1][t] + colp[2][t] + colp[3][t];
    if (i0 + t < NI && cc) atomicAdd(&Nv[i0 + t], cc);
    if (u0 + t < NU && rowc[t]) atomicAdd(&Nu[u0 + t], rowc[t]);
  }
}

// ---------------------------------------------------------------------------
// K2: P build (int8, x256 scale, KP-padded rows).
//   Pu[r*256+m][i] = rni8(msg_W[r][m][NU+i] * rsqrt(Nv[i]) * 256)
//   Pv[r*256+m][u] = rni8(msg_W[r][m][u]    * rsqrt(Nu[u]) * 256)
// ---------------------------------------------------------------------------
__global__ __launch_bounds__(256) void k_pbuild(const float* __restrict__ msgW,
                                                const int* __restrict__ Nu,
                                                const int* __restrict__ Nv,
                                                int8_t* __restrict__ Pu,
                                                int8_t* __restrict__ Pv) {
  const int b = blockIdx.x;                 // r*256 + m
  const float* src = msgW + (size_t)b * (NU + NI);
  for (int idx = threadIdx.x; idx < KP; idx += 256) {
    int8_t qv = 0, qu = 0;
    if (idx < NU) {
      const int cu = Nu[idx], cv = Nv[idx];
      const float su = cu > 0 ? rsqrtf((float)cu) * 256.0f : 0.f;
      const float sv = cv > 0 ? rsqrtf((float)cv) * 256.0f : 0.f;
      float xv = fminf(fmaxf(src[idx] * su, -127.f), 127.f);
      float xu = fminf(fmaxf(src[NU + idx] * sv, -127.f), 127.f);
      qv = (int8_t)__float2int_rn(xv);
      qu = (int8_t)__float2int_rn(xu);
    }
    Pv[(size_t)b * KP + idx] = qv;
    Pu[(size_t)b * KP + idx] = qu;
  }
}

// ---------------------------------------------------------------------------
// K3: barrier-free one-hot i8 MFMA GEMM (K=64 per MFMA).
//  - 4 waves/block, wave owns 32 cols; per-wave private 20KB LDS dbuf.
//  - counted per-wave vmcnt, NO __syncthreads in the K-loop.
//  - LDS 16B-unit XOR swizzle j' = j ^ ((col>>1)&3): conflict-free b128 reads.
//  - grid 504: bid&7 -> (side, bn, ks) = XCD-pure P slice; bid>>3 -> bm.
// ---------------------------------------------------------------------------
#define GLOAD_LDS(g, s) __builtin_amdgcn_global_load_lds( \
    (const __attribute__((address_space(1))) uint32_t*)(g), \
    (__attribute__((address_space(3))) uint32_t*)(s), 16, 0, 0)

static __device__ __forceinline__ uint32_t ohp(uint32_t sel, int r) {
  // one-hot i8: result byte = 0x01 iff adj byte == r+1 (adj bytes are 0..5)
  const uint32_t TL[5] = {0x00000100u, 0x00010000u, 0x01000000u, 0u, 0u};
  const uint32_t TH[5] = {0u, 0u, 0u, 0x00000001u, 0x00000100u};
  return __builtin_amdgcn_perm(TH[r], TL[r], sel);
}

__global__ __launch_bounds__(256, 2) void k_gemm(const int8_t* __restrict__ Au,
                                                 const int8_t* __restrict__ Av,
                                                 const int8_t* __restrict__ Pu,
                                                 const int8_t* __restrict__ Pv,
                                                 const int* __restrict__ Nu,
                                                 const int* __restrict__ Nv,
                                                 __hip_bfloat16* __restrict__ Hp) {
  __shared__ __attribute__((aligned(16))) char Bls[81920];

  const int bid = blockIdx.x;
  const int side = bid & 1, bn = (bid >> 1) & 1, ks = (bid >> 2) & 1;
  const int bm = bid >> 3;                          // 0..62
  const int8_t* __restrict__ A8 = side ? Av : Au;
  const int8_t* __restrict__ P  = side ? Pv : Pu;
  const int* __restrict__ cnt = side ? Nv : Nu;
  const int kbeg = ks * 2048;
  const int nsteps = ks ? 31 : 32;                  // 2048 / 1984 k

  const int t = threadIdx.x;
  const int w = t >> 6, l = t & 63;
  const int l15 = l & 15, l4 = l >> 4;

  // ---- staging: 10 gload_lds per wave per BK=64 tile ----
  // instr i: r = i>>1, ch = i&1; lane l covers col_local = ch*16 + (l>>2),
  // swizzled 16B unit j = (l&3) ^ ((l>>3)&3). HW writes lane l at dst + l*16.
  uint32_t soff[10];
  const int jsw = (l & 3) ^ ((l >> 3) & 3);
#pragma unroll
  for (int i = 0; i < 10; ++i) {
    const int r = i >> 1, ch = i & 1;
    const int colg = bn * 128 + w * 32 + ch * 16 + (l >> 2);
    soff[i] = (uint32_t)((r * 256 + colg) * KP) + (uint32_t)(jsw << 4);
  }
  const uint32_t lbase = (uint32_t)w * 20480u;

#define STAGE(bi, kk) { _Pragma("unroll") \
  for (int i_ = 0; i_ < 10; ++i_) \
    GLOAD_LDS(P + soff[i_] + (uint32_t)(kk), \
              (char*)Bls + lbase + (uint32_t)(bi) * 10240u + (uint32_t)(i_ << 10)); }

  // ---- read: lane (col=c*16+l15, k-unit l4) at swizzled unit l4^((l15>>1)&3)
  const uint32_t rbase =
      lbase + (uint32_t)(l15 << 6) + (uint32_t)(((l4 ^ ((l15 >> 1) & 3)) << 4));

  // ---- A: lane (row l15 (+g*16), k bytes [kk + l4*16, +16) ) ----
  const int8_t* pa = A8 + (size_t)(bm * 64 + l15) * KP + l4 * 16;

  i32x4 acc[4][2] = {};
  uint4 aC[4], aN[4];

  // prologue: S0, A0, S1  -> 24 outstanding vmem
  STAGE(0, kbeg);
#pragma unroll
  for (int g = 0; g < 4; ++g)
    aC[g] = *(const uint4*)(pa + (size_t)g * (16 * KP) + kbeg);
  asm volatile("" ::: "memory");
  STAGE(1, kbeg + 64);
#pragma unroll
  for (int g = 0; g < 4; ++g) aN[g] = aC[g];

  for (int st = 0; st < nsteps; ++st) {
    // drain S_t(10)+A_t(4); keep S_{t+1}(10) in flight (per-wave counter!)
    if (st + 1 < nsteps) asm volatile("s_waitcnt vmcnt(10)" ::: "memory");
    else                 asm volatile("s_waitcnt vmcnt(0)" ::: "memory");
    const uint32_t bufo = (st & 1) ? 10240u : 0u;
    uint4 B[10];
#pragma unroll
    for (int i = 0; i < 10; ++i)
      B[i] = *(const uint4*)((const char*)Bls + rbase + bufo + (uint32_t)(i << 10));
    // WAR fence: all reads of buf[st&1] complete before restaging into it
    asm volatile("s_waitcnt lgkmcnt(0)" ::: "memory");
    __builtin_amdgcn_sched_barrier(0);
    const int kk = kbeg + st * 64;
    if (st + 1 < nsteps) {
#pragma unroll
      for (int g = 0; g < 4; ++g)
        aN[g] = *(const uint4*)(pa + (size_t)g * (16 * KP) + kk + 64);
    }
    asm volatile("" ::: "memory");   // pin A-loads before stage loads (vmcnt order)
    if (st + 2 < nsteps) STAGE(st & 1, kk + 128);
    __builtin_amdgcn_s_setprio(1);
#pragma unroll
    for (int r = 0; r < 5; ++r) {
#pragma unroll
      for (int g = 0; g < 4; ++g) {
        uint4 af;
        af.x = ohp(aC[g].x, r); af.y = ohp(aC[g].y, r);
        af.z = ohp(aC[g].z, r); af.w = ohp(aC[g].w, r);
        const i32x4 a4 = __builtin_bit_cast(i32x4, af);
        acc[g][0] = __builtin_amdgcn_mfma_i32_16x16x64_i8(
            a4, __builtin_bit_cast(i32x4, B[r * 2 + 0]), acc[g][0], 0, 0, 0);
        acc[g][1] = __builtin_amdgcn_mfma_i32_16x16x64_i8(
            a4, __builtin_bit_cast(i32x4, B[r * 2 + 1]), acc[g][1], 0, 0, 0);
      }
    }
    __builtin_amdgcn_s_setprio(0);
#pragma unroll
    for (int g = 0; g < 4; ++g) aC[g] = aN[g];
  }

  // epilogue: scale by rsqrt(cnt)/256, store bf16 partial (relu deferred)
  __hip_bfloat16* hp = Hp + (size_t)(ks * 2 + side) * HP_STRIDE;
#pragma unroll
  for (int g = 0; g < 4; ++g) {
    const int rowb = bm * 64 + g * 16 + l4 * 4;
#pragma unroll
    for (int c = 0; c < 2; ++c) {
      const int ocol = bn * 128 + w * 32 + c * 16 + l15;
#pragma unroll
      for (int q = 0; q < 4; ++q) {
        const int orow = rowb + q;
        if (orow < 4000) {
          const int cv = cnt[orow];
          const float s = cv > 0 ? rsqrtf((float)cv) * (1.0f / 256.0f) : 0.f;
          hp[(size_t)orow * 256 + ocol] = __float2bfloat16((float)acc[g][c][q] * s);
        }
      }
    }
  }
#undef STAGE
}

// ---------------------------------------------------------------------------
// K4: fused stage 2 (MFMA). Hsum = relu(part0 + part1) (already scaled).
//   F = relu(sf@W1^T + b1);  out = relu(Hsum@dW^T + F@W2^T)
// grid 250 = 2 sides x 125, block 128.
// ---------------------------------------------------------------------------
__global__ __launch_bounds__(128) void k_out(const __hip_bfloat16* __restrict__ Hp,
                                             const float* __restrict__ usf,
                                             const float* __restrict__ vsf,
                                             const float* __restrict__ dW,
                                             const float* __restrict__ uW1,
                                             const float* __restrict__ ub1,
                                             const float* __restrict__ uW2,
                                             const float* __restrict__ vW1,
                                             const float* __restrict__ vb1,
                                             const float* __restrict__ vW2,
                                             float* __restrict__ out) {
  const int bid = blockIdx.x;
  const int side = bid / 125, rb = bid % 125;
  const int t = threadIdx.x, w = t >> 6, l = t & 63;
  const int l15 = l & 15, l4 = l >> 4;
  const int r0 = rb * 32 + w * 16;
  const float* __restrict__ sf = side ? vsf : usf;
  const float* __restrict__ W1 = side ? vW1 : uW1;
  const float* __restrict__ b1 = side ? vb1 : ub1;
  const float* __restrict__ W2 = side ? vW2 : uW2;
  const __hip_bfloat16* __restrict__ hp = Hp + (size_t)side * HP_STRIDE;

  const int myrow = r0 + l15;

  __shared__ __hip_bfloat16 lf[2][16][72];

  // ---- Phase A: F = relu(sf @ W1^T + b1) ----
  f32x4 fA[4] = {};
#pragma unroll
  for (int kk = 0; kk < 128; kk += 32) {
    const float* ps = sf + (size_t)myrow * 128 + kk + 8 * l4;
    const bf16x8 af = cvt8(*(const f32x4*)ps, *(const f32x4*)(ps + 4));
#pragma unroll
    for (int c = 0; c < 4; ++c) {
      const float* pw = W1 + (size_t)(c * 16 + l15) * 128 + kk + 8 * l4;
      const bf16x8 bf = cvt8(*(const f32x4*)pw, *(const f32x4*)(pw + 4));
      fA[c] = __builtin_amdgcn_mfma_f32_16x16x32_bf16(af, bf, fA[c], 0, 0, 0);
    }
  }
#pragma unroll
  for (int c = 0; c < 4; ++c) {
    const float bv = b1[c * 16 + l15];
#pragma unroll
    for (int reg = 0; reg < 4; ++reg) {
      float v = fA[c][reg] + bv;
      lf[w][l4 * 4 + reg][c * 16 + l15] = __float2bfloat16(v > 0.f ? v : 0.f);
    }
  }
  __syncthreads();

  // ---- Phase B: out = relu(Hsum@dW^T + F@W2^T) ----
  f32x4 oA[5] = {};
  const __hip_bfloat16* hbase = hp + (size_t)myrow * 256 + 8 * l4;
#pragma unroll
  for (int kk = 0; kk < 256; kk += 32) {
    const bf16x8 q0 = *(const bf16x8*)(hbase + kk);
    const bf16x8 q1 = *(const bf16x8*)(hbase + 2 * HP_STRIDE + kk);
    bf16x8 af;
#pragma unroll
    for (int j = 0; j < 8; ++j) {
      float hv = b2f(q0[j]) + b2f(q1[j]);
      af[j] = f2b(hv > 0.f ? hv : 0.f);
    }
#pragma unroll
    for (int c = 0; c < 5; ++c) {
      int oc = c * 16 + l15; if (oc > 74) oc = 74;   // clamp, stores guarded
      const float* pd = dW + (size_t)oc * 256 + kk + 8 * l4;
      const bf16x8 bf = cvt8(*(const f32x4*)pd, *(const f32x4*)(pd + 4));
      oA[c] = __builtin_amdgcn_mfma_f32_16x16x32_bf16(af, bf, oA[c], 0, 0, 0);
    }
  }
#pragma unroll
  for (int kk = 0; kk < 64; kk += 32) {
    const bf16x8 af = *(const bf16x8*)(&lf[w][l15][kk + 8 * l4]);
#pragma unroll
    for (int c = 0; c < 5; ++c) {
      int oc = c * 16 + l15; if (oc > 74) oc = 74;
      const float* pw = W2 + (size_t)oc * 64 + kk + 8 * l4;
      const bf16x8 bf = cvt8(*(const f32x4*)pw, *(const f32x4*)(pw + 4));
      oA[c] = __builtin_amdgcn_mfma_f32_16x16x32_bf16(af, bf, oA[c], 0, 0, 0);
    }
  }
  float* po = out + (size_t)side * (4000 * 75);
#pragma unroll
  for (int c = 0; c < 5; ++c) {
    const int oc = c * 16 + l15;
    if (oc < 75) {
#pragma unroll
      for (int reg = 0; reg < 4; ++reg) {
        const int orow = r0 + l4 * 4 + reg;
        const float v = oA[c][reg];
        po[(size_t)orow * 75 + oc] = v > 0.f ? v : 0.f;
      }
    }
  }
}

// ---------------------------------------------------------------------------
extern "C" void kernel_launch(void* const* d_in, const int* in_sizes, int n_in,
                              void* d_out, int out_size, void* d_ws, size_t ws_size,
                              hipStream_t stream) {
  const int* adj = (const int*)d_in[0];
  const float* usf = (const float*)d_in[1];
  const float* vsf = (const float*)d_in[2];
  const float* msgW = (const float*)d_in[3];
  const float* dW = (const float*)d_in[4];
  const float* uW1 = (const float*)d_in[5];
  const float* ub1 = (const float*)d_in[6];
  const float* uW2 = (const float*)d_in[7];
  const float* vW1 = (const float*)d_in[8];
  const float* vb1 = (const float*)d_in[9];
  const float* vW2 = (const float*)d_in[10];
  float* out = (float*)d_out;

  char* w = (char*)d_ws;
  const size_t A_BYTES = (size_t)KP * KP;              // 16,257,024
  const size_t P_BYTES = (size_t)RR * MM * KP;         // 5,160,960 (int8)
  const size_t HP_BYTES = (size_t)4 * HP_STRIDE * 2;   // 8,192,000 (bf16)
  int* Nu = (int*)w;
  int* Nv = (int*)(w + 16384);
  int8_t* Au = (int8_t*)(w + 32768);
  int8_t* Av = Au + A_BYTES;
  int8_t* Pu = (int8_t*)(w + 32768 + 2 * A_BYTES);
  int8_t* Pv = Pu + P_BYTES;
  __hip_bfloat16* Hp = (__hip_bfloat16*)(w + 32768 + 2 * A_BYTES + 2 * P_BYTES);
  const size_t need = 32768 + 2 * A_BYTES + 2 * P_BYTES + HP_BYTES;  // 51,060,736
  if (ws_size < need) return;

  hipMemsetAsync(w, 0, 32768, stream);
  k_trans<<<dim3(63, 63), 256, 0, stream>>>(adj, Au, Av, Nu, Nv);
  k_pbuild<<<1280, 256, 0, stream>>>(msgW, Nu, Nv, Pu, Pv);
  k_gemm<<<504, 256, 0, stream>>>(Au, Av, Pu, Pv, Nu, Nv, Hp);
  k_out<<<250, 128, 0, stream>>>(Hp, usf, vsf, dW, uW1, ub1, uW2, vW1, vb1, vW2,
                                 out);
}